// Round 16
// baseline (435.856 us; speedup 1.0000x reference)
//
#include <hip/hip_runtime.h>
#include <hip/hip_bf16.h>

#define BATCH 8
#define SEQ   2048
#define DIM   64
#define TSPLIT 8

typedef __attribute__((ext_vector_type(8))) short short8;
typedef __attribute__((ext_vector_type(4))) float floatx4;

// fast f32->bf16: +0x8000 then truncate (<=0.5ulp + 2^-17 bias; bf16 already 0.4% quant)
static __device__ __forceinline__ unsigned short f2bf(float x) {
    union { float f; unsigned u; } v; v.f = x;
    return (unsigned short)((v.u + 0x8000u) >> 16);
}
static __device__ __forceinline__ float bf2f(unsigned short u) {
    union { unsigned u; float f; } v; v.u = (unsigned)u << 16;
    return v.f;
}

#if __has_builtin(__builtin_amdgcn_sqrtf)
#define FSQRT(x) __builtin_amdgcn_sqrtf(x)
#else
#define FSQRT(x) sqrtf(x)
#endif
#if __has_builtin(__builtin_amdgcn_exp2f)
#define FEXP2(x) __builtin_amdgcn_exp2f(x)
#else
#define FEXP2(x) exp2f(x)
#endif

// log2(e)^2: folded into Qb/q2/k2 so wgt = exp2(-sqrt(seeded-MFMA result))
#define C2 2.0813689810056077f

// async global->LDS DMA, 16 B/lane; LDS dest = wave-uniform base + lane*16
static __device__ __forceinline__ void load_lds16(const void* g, void* l) {
    __builtin_amdgcn_global_load_lds(
        (const __attribute__((address_space(1))) void*)g,
        (__attribute__((address_space(3))) void*)l, 16, 0, 0);
}

// ---- fused prep ------------------------------------------------------------
// blocks [0,2048): Q/K bf16 cast, one float4/thread (single pass) + row norms.
//   Q holds -2*C2*q; q2/k2 hold C2*norm (folds the exp2 conversion into data).
//   K chunk-swizzled for the unpadded LDS tile.
// blocks [2048,2304): V -> Vt transpose (chunk-swizzled) + csum partials.
// block 2304: zero the 256 last-block-wins group counters.
#define QK_BLK 2048
#define VT_BLK 256

__global__ __launch_bounds__(256) void prep_all(
        const float* __restrict__ Q, const float* __restrict__ K,
        const float* __restrict__ V,
        unsigned short* __restrict__ Qb, unsigned short* __restrict__ Kb,
        unsigned short* __restrict__ Vt,
        float* __restrict__ q2, float* __restrict__ k2,
        float* __restrict__ csum_part, int* __restrict__ cnt) {
    int bid = blockIdx.x;
    if (bid < QK_BLK) {
        const int NQ = BATCH * SEQ * (DIM / 4);   // 262144 float4s in Q
        int gid = bid * 256 + threadIdx.x;
        const float* src; unsigned short* db; float* dn; int idx; float scl; int swz;
        if (gid < NQ) { src = Q; db = Qb; dn = q2; idx = gid;      scl = -2.f * C2; swz = 0; }
        else          { src = K; db = Kb; dn = k2; idx = gid - NQ; scl =  1.f;      swz = 1; }
        float4 v = ((const float4*)src)[idx];
        float s = v.x * v.x + v.y * v.y + v.z * v.z + v.w * v.w;   // raw row norm
        ushort4 o;
        o.x = f2bf(v.x * scl); o.y = f2bf(v.y * scl);
        o.z = f2bf(v.z * scl); o.w = f2bf(v.w * scl);
        int row = idx >> 4, j = idx & 15;
        int jo  = swz ? (j ^ ((row & 7) << 1)) : j;   // 16B-chunk XOR swizzle
        ((ushort4*)db)[(row << 4) | jo] = o;
        s += __shfl_xor(s, 1); s += __shfl_xor(s, 2);
        s += __shfl_xor(s, 4); s += __shfl_xor(s, 8);
        if (j == 0) dn[row] = s * C2;
    } else if (bid < QK_BLK + VT_BLK) {
        __shared__ float tile[64][65];
        __shared__ float psum[4][64];
        int vb = bid - QK_BLK;                    // vb = b*32 + tile
        int b  = vb >> 5;
        int t0 = (vb & 31) * 64;
        int i  = threadIdx.x;
        int d  = i & 63, g = i >> 6;
        float part = 0.f;
        #pragma unroll
        for (int p = 0; p < 16; ++p) {
            int tt = p * 4 + g;
            float v = V[((size_t)(b * SEQ + t0 + tt)) * DIM + d];
            tile[tt][d] = v;
            part += v;
        }
        psum[g][d] = part;
        __syncthreads();
        int tt = i & 63;
        #pragma unroll
        for (int p = 0; p < 16; ++p) {
            int dd = p * 4 + g;
            // chunk swizzle within the 64-key (128 B) slice
            Vt[((size_t)(b * DIM + dd)) * SEQ + t0 + (tt ^ ((dd & 7) << 3))] =
                f2bf(tile[tt][dd]);
        }
        if (i < 64)
            csum_part[vb * 64 + i] =
                psum[0][i] + psum[1][i] + psum[2][i] + psum[3][i];
    } else {
        cnt[threadIdx.x] = 0;                     // 256 group counters
    }
}

// ---- main: shifted-softmax gaussian attention + last-block finalize --------
// LAUNCH BOUNDS LESSON (r4/r12/r13): min-waves >= 5 caps unified VGPR+AGPR
// below this loop's ~86-reg need -> hot-loop scratch spill (r13: VGPR pinned
// to 40, WRITE 80MB). (256,4) = cap 128, no spill (r8/r14/r15 verified).
// r16: finalize fused via last-block-wins -- r12's "tail caused spill" was
// misattributed (r13 spilled WITHOUT the tail at (256,6)); tail pressure is
// ~30 regs after acc dies, safe under cap 128. Deletes the finalize dispatch
// and reads partials L2-hot.
__global__ __launch_bounds__(256, 4) void gauss_attn(
        const unsigned short* __restrict__ Qb, const unsigned short* __restrict__ Kb,
        const unsigned short* __restrict__ Vt, const float* __restrict__ q2,
        const float* __restrict__ k2, const float* __restrict__ csum_part,
        unsigned short* __restrict__ nbuf, float* __restrict__ dbuf,
        int* __restrict__ cnt, float* __restrict__ out) {
    __shared__ __align__(16) union {
        struct {
            unsigned short Kt[64 * 64];      // 8 KB (K tile, unpadded, swizzled)
            unsigned short Vv[64 * 64];      // 8 KB (V tile, unpadded, swizzled)
            unsigned short P[4][16 * 64];    // 8 KB (per-wave P', chunk-swizzled)
            float k2sh[64];                  // 256 B (k2 tile, coalesced staging)
            int   lastflag;
        } m;                                 // = 24836 B
        struct {
            float cps[4][64];                // csum partial groups
            float csh[64];                   // reduced V col-sums
            float rcp[64];                   // per-row 1/denominator
        } fin;                               // overlays m AFTER main loop only
    } sh;

    const int bid   = blockIdx.x;                 // grid = 8 * 32 * 8
    const int ts    = bid & 7;                    // key eighth
    const int qt    = (bid >> 3) & 31;            // 64-row q tile
    const int b     = bid >> 8;
    const int tid   = threadIdx.x;
    const int w     = tid >> 6;
    const int lane  = tid & 63;
    const int l15   = lane & 15;
    const int quad  = lane >> 4;
    const int qrow0 = qt * 64 + w * 16;           // this wave's 16 q-rows
    const int s7    = l15 & 7;                    // fragment de-swizzle key
    const int t00   = ts * 256;                   // this block's 256 keys

    const size_t kbase = (size_t)b * SEQ * DIM;   // shorts
    const size_t vbase = (size_t)b * DIM * SEQ;

    // Q fragments (A operand, holds -2*C2*q): A[m=lane&15][k=quad*8+j]
    short8 qf0 = *(const short8*)(Qb + ((size_t)(b * SEQ + qrow0 + l15)) * DIM + quad * 8);
    short8 qf1 = *(const short8*)(Qb + ((size_t)(b * SEQ + qrow0 + l15)) * DIM + 32 + quad * 8);
    floatx4 q2v = *(const floatx4*)(q2 + b * SEQ + qrow0 + quad * 4);
    const float* k2g = k2 + b * SEQ;

    floatx4 acc[4];
    #pragma unroll
    for (int nt = 0; nt < 4; ++nt) acc[nt] = (floatx4){0.f, 0.f, 0.f, 0.f};
    float dsum[4] = {0.f, 0.f, 0.f, 0.f};

    unsigned short* Pw = sh.m.P[w];

    #pragma unroll 1
    for (int it = 0; it < 4; ++it) {
        const int t0 = t00 + it * 64;
        __syncthreads();               // previous tile fully consumed
        {   // wave w stages its 16 K-rows and 16 V(d)-rows; 8 rows/instr
            #pragma unroll
            for (int i = 0; i < 2; ++i) {
                int r = w * 16 + i * 8;
                load_lds16(Kb + kbase + (size_t)(t0 + r + (lane >> 3)) * DIM + (lane & 7) * 8,
                           &sh.m.Kt[r * 64]);
                load_lds16(Vt + vbase + (size_t)(r + (lane >> 3)) * SEQ + t0 + (lane & 7) * 8,
                           &sh.m.Vv[r * 64]);
            }
            if (tid < 64) sh.m.k2sh[tid] = k2g[t0 + tid];   // 2 coalesced lines
        }
        __syncthreads();               // DMA drained (compiler inserts vmcnt(0))

        // ---- QK^T (C seeded with C2*(q2+k2) -> C2*d2 out of the MFMA) ----
        #pragma unroll
        for (int nt = 0; nt < 4; ++nt) {
            short8 kf0 = *(const short8*)&sh.m.Kt[(nt * 16 + l15) * 64 + ((quad ^ s7) << 3)];
            short8 kf1 = *(const short8*)&sh.m.Kt[(nt * 16 + l15) * 64 + (((4 | quad) ^ s7) << 3)];
            float k2n = sh.m.k2sh[nt * 16 + l15];
            floatx4 sc;
            #pragma unroll
            for (int r = 0; r < 4; ++r) sc[r] = q2v[r] + k2n;
            sc = __builtin_amdgcn_mfma_f32_16x16x32_bf16(qf0, kf0, sc, 0, 0, 0);
            sc = __builtin_amdgcn_mfma_f32_16x16x32_bf16(qf1, kf1, sc, 0, 0, 0);
            #pragma unroll
            for (int r = 0; r < 4; ++r) {
                float d2s = fmaxf(sc[r], 0.f);                 // C2 * d2
                float wgt = FEXP2(-FSQRT(d2s));                // exp(-dist)
                // expm1(wgt) quadratic; wgt < 3e-3 at 5 sigma -> rel err < 2e-6
                float pv = wgt * fmaf(wgt, 0.5f, 1.f);
                dsum[r] += pv;
                int row = quad * 4 + r;
                // chunk-swizzled P store: chunk (nt*2 | l15>>3) -> ^(row&7)
                Pw[row * 64 + ((((nt << 1) | (l15 >> 3)) ^ (row & 7)) << 3) + (l15 & 7)]
                    = f2bf(pv);
            }
        }

        // ---- P'V from LDS tiles (pf read de-swizzles with l15&7) ----
        #pragma unroll
        for (int tc = 0; tc < 2; ++tc) {
            short8 pf = *(const short8*)&Pw[l15 * 64 + (((tc * 4 + quad) ^ s7) << 3)];
            #pragma unroll
            for (int nt = 0; nt < 4; ++nt) {
                short8 vf = *(const short8*)
                    &sh.m.Vv[(nt * 16 + l15) * 64 + ((((tc << 2) | quad) ^ s7) << 3)];
                acc[nt] = __builtin_amdgcn_mfma_f32_16x16x32_bf16(pf, vf, acc[nt], 0, 0, 0);
            }
        }
    }

    // ---- partial epilogue: plain bf16 stores to this split's buffers ----
    #pragma unroll
    for (int r = 0; r < 4; ++r) {
        dsum[r] += __shfl_xor(dsum[r], 1);
        dsum[r] += __shfl_xor(dsum[r], 2);
        dsum[r] += __shfl_xor(dsum[r], 4);
        dsum[r] += __shfl_xor(dsum[r], 8);
    }
    unsigned short* nb = nbuf + (size_t)ts * (BATCH * SEQ * DIM);
    #pragma unroll
    for (int nt = 0; nt < 4; ++nt) {
        #pragma unroll
        for (int r = 0; r < 4; ++r) {
            nb[((size_t)(b * SEQ + qrow0 + quad * 4 + r)) * DIM + nt * 16 + l15] =
                f2bf(acc[nt][r]);
        }
    }
    if (l15 == 0) {
        #pragma unroll
        for (int r = 0; r < 4; ++r)
            dbuf[ts * (BATCH * SEQ) + b * SEQ + qrow0 + quad * 4 + r] = dsum[r];
    }

    // ---- last-block-wins fused finalize for this (b,qt) group ----
    __threadfence();                              // publish partials (device scope)
    __syncthreads();                              // everyone's stores issued
    if (tid == 0)
        sh.m.lastflag = (atomicAdd(&cnt[b * 32 + qt], 1) == TSPLIT - 1);
    __syncthreads();
    bool last = (sh.m.lastflag != 0);             // register copy: fin may alias
    __syncthreads();
    if (!last) return;
    __threadfence();                              // acquire others' partials

    {   // reduce csum partials (32 tiles) and denominators into LDS
        int g = tid >> 6, d = tid & 63;
        float cp = 0.f;
        #pragma unroll
        for (int p = 0; p < 8; ++p)
            cp += csum_part[(b * 32 + g * 8 + p) * 64 + d];
        sh.fin.cps[g][d] = cp;
        __syncthreads();
        if (tid < 64) {
            sh.fin.csh[tid] = sh.fin.cps[0][tid] + sh.fin.cps[1][tid]
                            + sh.fin.cps[2][tid] + sh.fin.cps[3][tid];
            float dn = 2048.f;
            #pragma unroll
            for (int t = 0; t < TSPLIT; ++t)
                dn += dbuf[t * (BATCH * SEQ) + b * SEQ + qt * 64 + tid];
            sh.fin.rcp[tid] = 1.f / dn;
        }
        __syncthreads();

        int row_l = tid >> 2, q4 = tid & 3;       // 4 threads/row, 4 f4 each
        size_t rowg = (size_t)(b * SEQ + qt * 64 + row_l);
        float rc = sh.fin.rcp[row_l];
        #pragma unroll
        for (int j = 0; j < 4; ++j) {
            int dq = q4 * 4 + j;
            float4 n = *(const float4*)&sh.fin.csh[dq * 4];
            #pragma unroll
            for (int t = 0; t < TSPLIT; ++t) {
                ushort4 p = *(const ushort4*)(nbuf + (size_t)t * (BATCH * SEQ * DIM)
                                                   + rowg * DIM + dq * 4);
                n.x += bf2f(p.x); n.y += bf2f(p.y);
                n.z += bf2f(p.z); n.w += bf2f(p.w);
            }
            float4 o = {n.x * rc, n.y * rc, n.z * rc, n.w * rc};
            *(float4*)(out + rowg * DIM + dq * 4) = o;
        }
    }
}

extern "C" void kernel_launch(void* const* d_in, const int* in_sizes, int n_in,
                              void* d_out, int out_size, void* d_ws, size_t ws_size,
                              hipStream_t stream) {
    const float* Q = (const float*)d_in[0];
    const float* K = (const float*)d_in[1];
    const float* V = (const float*)d_in[2];
    float* out = (float*)d_out;

    char* ws = (char*)d_ws;                       // ws_size = 256 MiB (proven r9)
    unsigned short* Qb = (unsigned short*)(ws);                        // 2 MB
    unsigned short* Kb = (unsigned short*)(ws + (2u << 20));           // 2 MB (swizzled)
    unsigned short* Vt = (unsigned short*)(ws + (4u << 20));           // 2 MB (swizzled)
    float* q2     = (float*)(ws + (6u << 20));                         // 64 KB
    float* k2     = (float*)(ws + (6u << 20) + (64u << 10));           // 64 KB
    float* cpart  = (float*)(ws + (6u << 20) + (128u << 10));          // 64 KB
    float* dbuf   = (float*)(ws + (6u << 20) + (192u << 10));          // 512 KB
    int*   cnt    = (int*)  (ws + (6u << 20) + (704u << 10));          // 1 KB
    unsigned short* nbuf = (unsigned short*)(ws + (7u << 20));         // 16 MB (bf16)

    prep_all<<<QK_BLK + VT_BLK + 1, 256, 0, stream>>>(
        Q, K, V, Qb, Kb, Vt, q2, k2, cpart, cnt);
    gauss_attn<<<BATCH * 32 * TSPLIT, 256, 0, stream>>>(
        Qb, Kb, Vt, q2, k2, cpart, nbuf, dbuf, cnt, out);
}

// Round 17
// 97.201 us; speedup vs baseline: 4.4841x; 4.4841x over previous
//
#include <hip/hip_runtime.h>
#include <hip/hip_bf16.h>

#define BATCH 8
#define SEQ   2048
#define DIM   64
#define TSPLIT 8

typedef __attribute__((ext_vector_type(8))) short short8;
typedef __attribute__((ext_vector_type(4))) float floatx4;

// fast f32->bf16: +0x8000 then truncate (<=0.5ulp + 2^-17 bias; bf16 already 0.4% quant)
static __device__ __forceinline__ unsigned short f2bf(float x) {
    union { float f; unsigned u; } v; v.f = x;
    return (unsigned short)((v.u + 0x8000u) >> 16);
}
static __device__ __forceinline__ float bf2f(unsigned short u) {
    union { unsigned u; float f; } v; v.u = (unsigned)u << 16;
    return v.f;
}

#if __has_builtin(__builtin_amdgcn_sqrtf)
#define FSQRT(x) __builtin_amdgcn_sqrtf(x)
#else
#define FSQRT(x) sqrtf(x)
#endif
#if __has_builtin(__builtin_amdgcn_exp2f)
#define FEXP2(x) __builtin_amdgcn_exp2f(x)
#else
#define FEXP2(x) exp2f(x)
#endif

// log2(e)^2: folded into Qb/q2/k2 so wgt = exp2(-sqrt(seeded-MFMA result))
#define C2 2.0813689810056077f

// async global->LDS DMA, 16 B/lane; LDS dest = wave-uniform base + lane*16
static __device__ __forceinline__ void load_lds16(const void* g, void* l) {
    __builtin_amdgcn_global_load_lds(
        (const __attribute__((address_space(1))) void*)g,
        (__attribute__((address_space(3))) void*)l, 16, 0, 0);
}

// ---- fused prep ------------------------------------------------------------
// blocks [0,2048): Q/K bf16 cast, one float4/thread (single pass) + row norms.
//   Q holds -2*C2*q; q2/k2 hold C2*norm (folds the exp2 conversion into data).
//   K chunk-swizzled for the unpadded LDS tile.
// blocks [2048,2304): V -> Vt transpose (chunk-swizzled) + csum partials.
#define QK_BLK 2048
#define VT_BLK 256

__global__ __launch_bounds__(256) void prep_all(
        const float* __restrict__ Q, const float* __restrict__ K,
        const float* __restrict__ V,
        unsigned short* __restrict__ Qb, unsigned short* __restrict__ Kb,
        unsigned short* __restrict__ Vt,
        float* __restrict__ q2, float* __restrict__ k2,
        float* __restrict__ csum_part) {
    int bid = blockIdx.x;
    if (bid < QK_BLK) {
        const int NQ = BATCH * SEQ * (DIM / 4);   // 262144 float4s in Q
        int gid = bid * 256 + threadIdx.x;
        const float* src; unsigned short* db; float* dn; int idx; float scl; int swz;
        if (gid < NQ) { src = Q; db = Qb; dn = q2; idx = gid;      scl = -2.f * C2; swz = 0; }
        else          { src = K; db = Kb; dn = k2; idx = gid - NQ; scl =  1.f;      swz = 1; }
        float4 v = ((const float4*)src)[idx];
        float s = v.x * v.x + v.y * v.y + v.z * v.z + v.w * v.w;   // raw row norm
        ushort4 o;
        o.x = f2bf(v.x * scl); o.y = f2bf(v.y * scl);
        o.z = f2bf(v.z * scl); o.w = f2bf(v.w * scl);
        int row = idx >> 4, j = idx & 15;
        int jo  = swz ? (j ^ ((row & 7) << 1)) : j;   // 16B-chunk XOR swizzle
        ((ushort4*)db)[(row << 4) | jo] = o;
        s += __shfl_xor(s, 1); s += __shfl_xor(s, 2);
        s += __shfl_xor(s, 4); s += __shfl_xor(s, 8);
        if (j == 0) dn[row] = s * C2;
    } else {
        __shared__ float tile[64][65];
        __shared__ float psum[4][64];
        int vb = bid - QK_BLK;                    // vb = b*32 + tile
        int b  = vb >> 5;
        int t0 = (vb & 31) * 64;
        int i  = threadIdx.x;
        int d  = i & 63, g = i >> 6;
        float part = 0.f;
        #pragma unroll
        for (int p = 0; p < 16; ++p) {
            int tt = p * 4 + g;
            float v = V[((size_t)(b * SEQ + t0 + tt)) * DIM + d];
            tile[tt][d] = v;
            part += v;
        }
        psum[g][d] = part;
        __syncthreads();
        int tt = i & 63;
        #pragma unroll
        for (int p = 0; p < 16; ++p) {
            int dd = p * 4 + g;
            // chunk swizzle within the 64-key (128 B) slice
            Vt[((size_t)(b * DIM + dd)) * SEQ + t0 + (tt ^ ((dd & 7) << 3))] =
                f2bf(tile[tt][dd]);
        }
        if (i < 64)
            csum_part[vb * 64 + i] =
                psum[0][i] + psum[1][i] + psum[2][i] + psum[3][i];
    }
}

// ---- main: shifted-softmax gaussian attention ------------------------------
// LAUNCH BOUNDS LESSON (r4/r12/r13): min-waves >= 5 caps the unified
// VGPR+AGPR budget below this loop's ~86-reg need -> hot-loop scratch spill.
// (256,4) = cap 128, no spill (r8/r14/r15 verified).
// FUSION LESSON (r11/r16): cooperative launch fails under this harness, and
// in-kernel cross-block handshakes (__threadfence device-scope) cost an L2
// writeback per fence on 8-XCD CDNA4 -> 2048 blocks x fence ~= 400us. The
// kernel-boundary barrier (separate finalize dispatch) does ONE flush total.
// This 3-dispatch r15 form is the proven optimum (98.3us).
__global__ __launch_bounds__(256, 4) void gauss_attn(
        const unsigned short* __restrict__ Qb, const unsigned short* __restrict__ Kb,
        const unsigned short* __restrict__ Vt, const float* __restrict__ q2,
        const float* __restrict__ k2,
        unsigned short* __restrict__ nbuf, float* __restrict__ dbuf) {
    __shared__ __align__(16) struct {
        unsigned short Kt[64 * 64];      // 8 KB (K tile, unpadded, swizzled)
        unsigned short Vv[64 * 64];      // 8 KB (V tile, unpadded, swizzled)
        unsigned short P[4][16 * 64];    // 8 KB (per-wave P', chunk-swizzled)
        float k2sh[64];                  // 256 B (k2 tile, coalesced staging)
    } sh;                                // = 24832 B

    const int bid   = blockIdx.x;                 // grid = 8 * 32 * 8
    const int ts    = bid & 7;                    // key eighth
    const int qt    = (bid >> 3) & 31;            // 64-row q tile
    const int b     = bid >> 8;
    const int tid   = threadIdx.x;
    const int w     = tid >> 6;
    const int lane  = tid & 63;
    const int l15   = lane & 15;
    const int quad  = lane >> 4;
    const int qrow0 = qt * 64 + w * 16;           // this wave's 16 q-rows
    const int s7    = l15 & 7;                    // fragment de-swizzle key
    const int t00   = ts * 256;                   // this block's 256 keys

    const size_t kbase = (size_t)b * SEQ * DIM;   // shorts
    const size_t vbase = (size_t)b * DIM * SEQ;

    // Q fragments (A operand, holds -2*C2*q): A[m=lane&15][k=quad*8+j]
    short8 qf0 = *(const short8*)(Qb + ((size_t)(b * SEQ + qrow0 + l15)) * DIM + quad * 8);
    short8 qf1 = *(const short8*)(Qb + ((size_t)(b * SEQ + qrow0 + l15)) * DIM + 32 + quad * 8);
    floatx4 q2v = *(const floatx4*)(q2 + b * SEQ + qrow0 + quad * 4);
    const float* k2g = k2 + b * SEQ;

    floatx4 acc[4];
    #pragma unroll
    for (int nt = 0; nt < 4; ++nt) acc[nt] = (floatx4){0.f, 0.f, 0.f, 0.f};
    float dsum[4] = {0.f, 0.f, 0.f, 0.f};

    unsigned short* Pw = sh.P[w];

    #pragma unroll 1
    for (int it = 0; it < 4; ++it) {
        const int t0 = t00 + it * 64;
        __syncthreads();               // previous tile fully consumed
        {   // wave w stages its 16 K-rows and 16 V(d)-rows; 8 rows/instr
            #pragma unroll
            for (int i = 0; i < 2; ++i) {
                int r = w * 16 + i * 8;
                load_lds16(Kb + kbase + (size_t)(t0 + r + (lane >> 3)) * DIM + (lane & 7) * 8,
                           &sh.Kt[r * 64]);
                load_lds16(Vt + vbase + (size_t)(r + (lane >> 3)) * SEQ + t0 + (lane & 7) * 8,
                           &sh.Vv[r * 64]);
            }
            if (tid < 64) sh.k2sh[tid] = k2g[t0 + tid];   // 2 coalesced lines
        }
        __syncthreads();               // DMA drained (compiler inserts vmcnt(0))

        // ---- QK^T (C seeded with C2*(q2+k2) -> C2*d2 out of the MFMA) ----
        #pragma unroll
        for (int nt = 0; nt < 4; ++nt) {
            short8 kf0 = *(const short8*)&sh.Kt[(nt * 16 + l15) * 64 + ((quad ^ s7) << 3)];
            short8 kf1 = *(const short8*)&sh.Kt[(nt * 16 + l15) * 64 + (((4 | quad) ^ s7) << 3)];
            float k2n = sh.k2sh[nt * 16 + l15];
            floatx4 sc;
            #pragma unroll
            for (int r = 0; r < 4; ++r) sc[r] = q2v[r] + k2n;
            sc = __builtin_amdgcn_mfma_f32_16x16x32_bf16(qf0, kf0, sc, 0, 0, 0);
            sc = __builtin_amdgcn_mfma_f32_16x16x32_bf16(qf1, kf1, sc, 0, 0, 0);
            #pragma unroll
            for (int r = 0; r < 4; ++r) {
                float d2s = fmaxf(sc[r], 0.f);                 // C2 * d2
                float wgt = FEXP2(-FSQRT(d2s));                // exp(-dist)
                // expm1(wgt) quadratic; wgt < 3e-3 at 5 sigma -> rel err < 2e-6
                float pv = wgt * fmaf(wgt, 0.5f, 1.f);
                dsum[r] += pv;
                int row = quad * 4 + r;
                // chunk-swizzled P store: chunk (nt*2 | l15>>3) -> ^(row&7)
                Pw[row * 64 + ((((nt << 1) | (l15 >> 3)) ^ (row & 7)) << 3) + (l15 & 7)]
                    = f2bf(pv);
            }
        }

        // ---- P'V from LDS tiles (pf read de-swizzles with l15&7) ----
        #pragma unroll
        for (int tc = 0; tc < 2; ++tc) {
            short8 pf = *(const short8*)&Pw[l15 * 64 + (((tc * 4 + quad) ^ s7) << 3)];
            #pragma unroll
            for (int nt = 0; nt < 4; ++nt) {
                short8 vf = *(const short8*)
                    &sh.Vv[(nt * 16 + l15) * 64 + ((((tc << 2) | quad) ^ s7) << 3)];
                acc[nt] = __builtin_amdgcn_mfma_f32_16x16x32_bf16(pf, vf, acc[nt], 0, 0, 0);
            }
        }
    }

    // ---- partial epilogue: plain bf16 stores to this split's buffers ----
    #pragma unroll
    for (int r = 0; r < 4; ++r) {
        dsum[r] += __shfl_xor(dsum[r], 1);
        dsum[r] += __shfl_xor(dsum[r], 2);
        dsum[r] += __shfl_xor(dsum[r], 4);
        dsum[r] += __shfl_xor(dsum[r], 8);
    }
    unsigned short* nb = nbuf + (size_t)ts * (BATCH * SEQ * DIM);
    #pragma unroll
    for (int nt = 0; nt < 4; ++nt) {
        #pragma unroll
        for (int r = 0; r < 4; ++r) {
            nb[((size_t)(b * SEQ + qrow0 + quad * 4 + r)) * DIM + nt * 16 + l15] =
                f2bf(acc[nt][r]);
        }
    }
    if (l15 == 0) {
        #pragma unroll
        for (int r = 0; r < 4; ++r)
            dbuf[ts * (BATCH * SEQ) + b * SEQ + qrow0 + quad * 4 + r] = dsum[r];
    }
}

// ---- finalize: out = (sum_ts nbuf + csum) / (S + sum_ts dbuf) --------------
// csum reduced block-cooperatively through LDS (one 8KB pass per block).
__global__ __launch_bounds__(256) void finalize(
        const unsigned short* __restrict__ nbuf, const float* __restrict__ dbuf,
        const float* __restrict__ csum_part, float* __restrict__ out) {
    __shared__ float psh[4][64];
    __shared__ float csh[64];
    int bid = blockIdx.x, tid = threadIdx.x;     // 1024 blocks; 16 rows/block
    int b = bid >> 7;                            // all rows in a block share b
    {
        int g = tid >> 6, d = tid & 63;
        float cp = 0.f;
        #pragma unroll
        for (int p = 0; p < 8; ++p)
            cp += csum_part[(b * 32 + g * 8 + p) * 64 + d];
        psh[g][d] = cp;
    }
    __syncthreads();
    if (tid < 64)
        csh[tid] = psh[0][tid] + psh[1][tid] + psh[2][tid] + psh[3][tid];
    __syncthreads();

    int gid = bid * 256 + tid;                   // one float4 of d per thread
    int row = gid >> 4;                          // b*SEQ + s
    int dq  = gid & 15;
    float den = 2048.f;
    #pragma unroll
    for (int t = 0; t < TSPLIT; ++t) den += dbuf[t * (BATCH * SEQ) + row];
    float rcp = 1.f / den;
    float4 n = *(const float4*)&csh[dq * 4];
    #pragma unroll
    for (int t = 0; t < TSPLIT; ++t) {
        ushort4 p = *(const ushort4*)(nbuf + (size_t)t * (BATCH * SEQ * DIM)
                                           + (size_t)row * DIM + dq * 4);
        n.x += bf2f(p.x); n.y += bf2f(p.y); n.z += bf2f(p.z); n.w += bf2f(p.w);
    }
    float4 o = {n.x * rcp, n.y * rcp, n.z * rcp, n.w * rcp};
    *(float4*)(out + (size_t)row * DIM + dq * 4) = o;
}

extern "C" void kernel_launch(void* const* d_in, const int* in_sizes, int n_in,
                              void* d_out, int out_size, void* d_ws, size_t ws_size,
                              hipStream_t stream) {
    const float* Q = (const float*)d_in[0];
    const float* K = (const float*)d_in[1];
    const float* V = (const float*)d_in[2];
    float* out = (float*)d_out;

    char* ws = (char*)d_ws;                       // ws_size = 256 MiB (proven r9)
    unsigned short* Qb = (unsigned short*)(ws);                        // 2 MB
    unsigned short* Kb = (unsigned short*)(ws + (2u << 20));           // 2 MB (swizzled)
    unsigned short* Vt = (unsigned short*)(ws + (4u << 20));           // 2 MB (swizzled)
    float* q2     = (float*)(ws + (6u << 20));                         // 64 KB
    float* k2     = (float*)(ws + (6u << 20) + (64u << 10));           // 64 KB
    float* cpart  = (float*)(ws + (6u << 20) + (128u << 10));          // 64 KB
    float* dbuf   = (float*)(ws + (6u << 20) + (192u << 10));          // 512 KB
    unsigned short* nbuf = (unsigned short*)(ws + (7u << 20));         // 16 MB (bf16)

    prep_all<<<QK_BLK + VT_BLK, 256, 0, stream>>>(
        Q, K, V, Qb, Kb, Vt, q2, k2, cpart);
    gauss_attn<<<BATCH * 32 * TSPLIT, 256, 0, stream>>>(
        Qb, Kb, Vt, q2, k2, nbuf, dbuf);
    finalize<<<(BATCH * SEQ * DIM / 4) / 256, 256, 0, stream>>>(
        nbuf, dbuf, cpart, out);
}